// Round 1
// baseline (435.567 us; speedup 1.0000x reference)
//
#include <hip/hip_runtime.h>
#include <math.h>

// SoftSkeletonize: out = relu(img - dilate3(erode3(img))), (2,1,192,256,256) f32.
// erode = min-pool 3x3x3 (pad +inf), dilate = max-pool 3x3x3 (pad -inf).
//
// v2: z-direction pipelines in REGISTERS (per-position => same thread each
// plane): pmin/sprev carry the erode z-min, t2A/B/C carry the 2D-max planes,
// rwA/B/C carry raw centers. LDS holds only ONE raw plane + ONE eroded plane.
// All LDS access is b128-vectorized (8-wide thread strips), 2 barriers/plane,
// next raw plane software-prefetched into registers during compute.
//
// v3: occupancy push. rocprof on v2: dur 74.6us, HBM 2.96 TB/s (47% of
// achievable), VALUBusy 21%, Occupancy 27% -> latency-bound. Grid was 768
// blocks = exactly 3/CU (matching launch_bounds(256,3)). CD 16->8 doubles the
// grid to 1536 = 6 blocks/CU; LDS 21.5KB*6=129KB<160KB and VGPR 72<=85 both
// fit, so launch_bounds(256,6). Cost: z-halo overhead 12/8 vs 20/16 (+20%
// plane iters, fetch ~117->~145MB) -- cheap vs 2x concurrency.

#define D_ 192
#define H_ 256
#define W_ 256
#define NB 2
#define TH 32
#define TW 64
#define CD 8
#define NCHUNK (D_ / CD)      // 24

#define RAW_H (TH + 4)        // 36 rows  <-> gh = h0-2 .. h0+33
#define RAW_W (TW + 8)        // 72 cols  <-> gw = w0-4 .. w0+67
#define RAW_S 76              // padded stride (76 mod 32 = 12 -> bank spread)
#define EB_H  (TH + 2)        // 34 rows  <-> gh = h0-1 .. h0+32
#define EB_W  (TW + 8)        // 72 cols  <-> gw = w0-4 .. w0+67
#define EB_S  76

#define NRAWF4 (RAW_H * (RAW_W / 4))   // 648 float4 cells
#define NBTASK (EB_H * (EB_W / 8))     // 306 8-wide tasks

__device__ __forceinline__ float min3f(float a, float b, float c) {
    return fminf(fminf(a, b), c);
}
__device__ __forceinline__ float max3f(float a, float b, float c) {
    return fmaxf(fmaxf(a, b), c);
}

__global__ __launch_bounds__(256, 6)
void soft_skel_v3(const float* __restrict__ img, float* __restrict__ out) {
    __shared__ __align__(16) float raw[RAW_H][RAW_S];
    __shared__ __align__(16) float ebuf[EB_H][EB_S];

    const int tid = threadIdx.x;
    const int w0 = blockIdx.x * TW;
    const int h0 = blockIdx.y * TH;
    const int n  = blockIdx.z / NCHUNK;
    const int ch = blockIdx.z - n * NCHUNK;
    const int z0 = ch * CD;

    const float* vol  = img + (size_t)n * (D_ * H_ * W_);
    float*       ovol = out + (size_t)n * (D_ * H_ * W_);

    const float PINF = INFINITY;

    // ---- A-stage per-thread geometry: 3 float4 slots cover the 36x72 region
    bool a_slot[3], a_img[3];
    int  a_lds[3], a_off[3];
    #pragma unroll
    for (int k = 0; k < 3; ++k) {
        int idx = tid + 256 * k;
        bool slot = idx < NRAWF4;
        int row = idx / (RAW_W / 4);           // /18
        int cg  = idx - row * (RAW_W / 4);
        int gh = h0 - 2 + row;
        int gw = w0 - 4 + 4 * cg;
        a_slot[k] = slot;
        a_img[k]  = slot && (gh >= 0) && (gh < H_) && (gw >= 0) && (gw <= W_ - 4);
        a_off[k]  = gh * W_ + gw;
        a_lds[k]  = slot ? (row * RAW_S + 4 * cg) : 0;
    }

    // ---- B-stage task geometry (8-wide strips over 34x72 region)
    const int  r0 = tid / 9;
    const int  c0 = (tid - r0 * 9) * 8;
    const bool has1 = tid < (NBTASK - 256);    // 50 threads take a 2nd task
    const int  t1 = tid + 256;
    const int  r1 = t1 / 9;
    const int  c1 = (t1 - r1 * 9) * 8;

    // ---- D/E geometry: thread owns tile row ty, cols xx..xx+7
    const int ty = tid >> 3;
    const int xx = (tid & 7) * 8;

    // ---- register z-pipelines
    float pm0[8], sp0[8], pm1[8], sp1[8];      // erode z-min state per B task
    float t2A[8], t2B[8], t2C[8];              // 2D-max planes z-1, z, z+1
    float rwA[8], rwB[8], rwC[8];              // raw centers z, z+1, z+2
    #pragma unroll
    for (int j = 0; j < 8; ++j) {
        pm0[j] = sp0[j] = pm1[j] = sp1[j] = PINF;
        t2A[j] = t2B[j] = 0.f;
        rwA[j] = rwB[j] = 0.f;
    }

    auto prefetch = [&](int zz, float4 L[3]) {
        const bool zok = (zz >= 0) && (zz < D_);
        const float* plane = vol + (size_t)zz * (H_ * W_);
        #pragma unroll
        for (int k = 0; k < 3; ++k) {
            float4 v = make_float4(PINF, PINF, PINF, PINF);
            if (zok && a_img[k]) v = *(const float4*)(plane + a_off[k]);
            L[k] = v;
        }
    };

    // B task: 2D 3x3 min of raw -> s; e(zz-1) = min(pm, s) (masked); update pipe
    auto btask = [&](int r, int cb, float pm[8], float sp[8], bool zeok) {
        float vm[10];
        {
            const float* p0 = &raw[r][0];
            const float* p1 = &raw[r + 1][0];
            const float* p2 = &raw[r + 2][0];
            int cl = cb - 1; if (cl < 0) cl = 0;
            int cr = cb + 8; if (cr > RAW_W - 1) cr = RAW_W - 1;
            vm[0] = min3f(p0[cl], p1[cl], p2[cl]);
            vm[9] = min3f(p0[cr], p1[cr], p2[cr]);
            float4 q00 = *(const float4*)(p0 + cb);
            float4 q01 = *(const float4*)(p0 + cb + 4);
            float4 q10 = *(const float4*)(p1 + cb);
            float4 q11 = *(const float4*)(p1 + cb + 4);
            float4 q20 = *(const float4*)(p2 + cb);
            float4 q21 = *(const float4*)(p2 + cb + 4);
            vm[1] = min3f(q00.x, q10.x, q20.x);
            vm[2] = min3f(q00.y, q10.y, q20.y);
            vm[3] = min3f(q00.z, q10.z, q20.z);
            vm[4] = min3f(q00.w, q10.w, q20.w);
            vm[5] = min3f(q01.x, q11.x, q21.x);
            vm[6] = min3f(q01.y, q11.y, q21.y);
            vm[7] = min3f(q01.z, q11.z, q21.z);
            vm[8] = min3f(q01.w, q11.w, q21.w);
        }
        float s[8];
        #pragma unroll
        for (int j = 0; j < 8; ++j) s[j] = min3f(vm[j], vm[j + 1], vm[j + 2]);

        const bool rok = zeok && ((unsigned)(h0 - 1 + r) < (unsigned)H_);
        float e[8];
        #pragma unroll
        for (int j = 0; j < 8; ++j) {
            float ev = fminf(pm[j], s[j]);
            bool ok = rok && ((unsigned)(w0 - 4 + cb + j) < (unsigned)W_);
            e[j] = ok ? ev : -PINF;
            pm[j] = fminf(sp[j], s[j]);
            sp[j] = s[j];
        }
        *(float4*)&ebuf[r][cb]     = make_float4(e[0], e[1], e[2], e[3]);
        *(float4*)&ebuf[r][cb + 4] = make_float4(e[4], e[5], e[6], e[7]);
    };

    float4 L[3];
    prefetch(z0 - 2, L);
    const int zzend = z0 + CD + 1;

    for (int zz = z0 - 2; zz <= zzend; ++zz) {
        // ---- A: commit prefetched raw plane zz to LDS, start loading zz+1
        #pragma unroll
        for (int k = 0; k < 3; ++k)
            if (a_slot[k]) *(float4*)(&raw[0][0] + a_lds[k]) = L[k];
        if (zz < zzend) prefetch(zz + 1, L);
        __syncthreads();

        // ---- A2: capture raw centers of plane zz (for output zz-2 later)
        {
            float4 v0 = *(const float4*)&raw[ty + 2][xx + 4];
            float4 v1 = *(const float4*)&raw[ty + 2][xx + 8];
            rwC[0] = v0.x; rwC[1] = v0.y; rwC[2] = v0.z; rwC[3] = v0.w;
            rwC[4] = v1.x; rwC[5] = v1.y; rwC[6] = v1.z; rwC[7] = v1.w;
        }

        // ---- B: s2d(zz) + full erode e(zz-1) -> ebuf
        const int  ze   = zz - 1;
        const bool zeok = (ze >= 0) && (ze < D_);
        btask(r0, c0, pm0, sp0, zeok);
        if (has1) btask(r1, c1, pm1, sp1, zeok);
        __syncthreads();

        // ---- D: 2D 3x3 max of e(zz-1) -> t2C (registers)
        {
            float vm[10];
            const float* p0 = &ebuf[ty][0];
            const float* p1 = &ebuf[ty + 1][0];
            const float* p2 = &ebuf[ty + 2][0];
            vm[0] = max3f(p0[xx + 3], p1[xx + 3], p2[xx + 3]);
            vm[9] = max3f(p0[xx + 12], p1[xx + 12], p2[xx + 12]);
            float4 q00 = *(const float4*)(p0 + xx + 4);
            float4 q01 = *(const float4*)(p0 + xx + 8);
            float4 q10 = *(const float4*)(p1 + xx + 4);
            float4 q11 = *(const float4*)(p1 + xx + 8);
            float4 q20 = *(const float4*)(p2 + xx + 4);
            float4 q21 = *(const float4*)(p2 + xx + 8);
            vm[1] = max3f(q00.x, q10.x, q20.x);
            vm[2] = max3f(q00.y, q10.y, q20.y);
            vm[3] = max3f(q00.z, q10.z, q20.z);
            vm[4] = max3f(q00.w, q10.w, q20.w);
            vm[5] = max3f(q01.x, q11.x, q21.x);
            vm[6] = max3f(q01.y, q11.y, q21.y);
            vm[7] = max3f(q01.z, q11.z, q21.z);
            vm[8] = max3f(q01.w, q11.w, q21.w);
            #pragma unroll
            for (int j = 0; j < 8; ++j) t2C[j] = max3f(vm[j], vm[j + 1], vm[j + 2]);
        }

        // ---- E: output plane z = zz-2: relu(raw - max over t2 planes)
        if (zz >= z0 + 2) {
            const int z = zz - 2;
            float* op = ovol + ((size_t)z * H_ + (h0 + ty)) * W_ + (w0 + xx);
            float o[8];
            #pragma unroll
            for (int j = 0; j < 8; ++j) {
                float opened = max3f(t2A[j], t2B[j], t2C[j]);
                float v = rwA[j] - opened;
                o[j] = v > 0.f ? v : 0.f;
            }
            *(float4*)op       = make_float4(o[0], o[1], o[2], o[3]);
            *(float4*)(op + 4) = make_float4(o[4], o[5], o[6], o[7]);
        }

        // ---- shift register pipelines
        #pragma unroll
        for (int j = 0; j < 8; ++j) {
            t2A[j] = t2B[j]; t2B[j] = t2C[j];
            rwA[j] = rwB[j]; rwB[j] = rwC[j];
        }
    }
}

extern "C" void kernel_launch(void* const* d_in, const int* in_sizes, int n_in,
                              void* d_out, int out_size, void* d_ws, size_t ws_size,
                              hipStream_t stream) {
    const float* img = (const float*)d_in[0];
    float* out = (float*)d_out;

    dim3 grid(W_ / TW, H_ / TH, NB * NCHUNK);   // (4, 8, 48) = 1536 blocks
    dim3 block(256);
    soft_skel_v3<<<grid, block, 0, stream>>>(img, out);
}

// Round 2
// 231.389 us; speedup vs baseline: 1.8824x; 1.8824x over previous
//
#include <hip/hip_runtime.h>
#include <math.h>

// SoftSkeletonize: out = relu(img - dilate3(erode3(img))), (2,1,192,256,256) f32.
// erode = min-pool 3x3x3 (pad +inf), dilate = max-pool 3x3x3 (pad -inf).
//
// v2: z-direction pipelines in REGISTERS (per-position => same thread each
// plane): pmin/sprev carry the erode z-min, t2A/B/C carry the 2D-max planes,
// rwA/B/C carry raw centers. LDS holds only ONE raw plane + ONE eroded plane.
// All LDS access is b128-vectorized (8-wide thread strips), 2 barriers/plane,
// next raw plane software-prefetched into registers during compute.
//
// v3 FAILED: launch_bounds(256,6) forced VGPR 72->40; the ~92 floats of
// register pipeline state spilled to scratch (WRITE_SIZE 98->744MB, dur
// 74.6->322us). Lesson: this kernel NEEDS ~72 VGPRs; occupancy quantum
// (m69: steps at 64/128) caps it at 4 waves/EU.
//
// v4: launch_bounds(256,4) (VGPR cap 128 -> no spill, ~72 used) + CD=12 so
// grid = 1024 blocks = exactly 4 resident blocks/CU (16 waves, 50% occ vs
// v2's 27%). z-halo tax only 16/12=1.33x (vs 1.5x at CD=8).

#define D_ 192
#define H_ 256
#define W_ 256
#define NB 2
#define TH 32
#define TW 64
#define CD 12
#define NCHUNK (D_ / CD)      // 16

#define RAW_H (TH + 4)        // 36 rows  <-> gh = h0-2 .. h0+33
#define RAW_W (TW + 8)        // 72 cols  <-> gw = w0-4 .. w0+67
#define RAW_S 76              // padded stride (76 mod 32 = 12 -> bank spread)
#define EB_H  (TH + 2)        // 34 rows  <-> gh = h0-1 .. h0+32
#define EB_W  (TW + 8)        // 72 cols  <-> gw = w0-4 .. w0+67
#define EB_S  76

#define NRAWF4 (RAW_H * (RAW_W / 4))   // 648 float4 cells
#define NBTASK (EB_H * (EB_W / 8))     // 306 8-wide tasks

__device__ __forceinline__ float min3f(float a, float b, float c) {
    return fminf(fminf(a, b), c);
}
__device__ __forceinline__ float max3f(float a, float b, float c) {
    return fmaxf(fmaxf(a, b), c);
}

__global__ __launch_bounds__(256, 4)
void soft_skel_v4(const float* __restrict__ img, float* __restrict__ out) {
    __shared__ __align__(16) float raw[RAW_H][RAW_S];
    __shared__ __align__(16) float ebuf[EB_H][EB_S];

    const int tid = threadIdx.x;
    const int w0 = blockIdx.x * TW;
    const int h0 = blockIdx.y * TH;
    const int n  = blockIdx.z / NCHUNK;
    const int ch = blockIdx.z - n * NCHUNK;
    const int z0 = ch * CD;

    const float* vol  = img + (size_t)n * (D_ * H_ * W_);
    float*       ovol = out + (size_t)n * (D_ * H_ * W_);

    const float PINF = INFINITY;

    // ---- A-stage per-thread geometry: 3 float4 slots cover the 36x72 region
    bool a_slot[3], a_img[3];
    int  a_lds[3], a_off[3];
    #pragma unroll
    for (int k = 0; k < 3; ++k) {
        int idx = tid + 256 * k;
        bool slot = idx < NRAWF4;
        int row = idx / (RAW_W / 4);           // /18
        int cg  = idx - row * (RAW_W / 4);
        int gh = h0 - 2 + row;
        int gw = w0 - 4 + 4 * cg;
        a_slot[k] = slot;
        a_img[k]  = slot && (gh >= 0) && (gh < H_) && (gw >= 0) && (gw <= W_ - 4);
        a_off[k]  = gh * W_ + gw;
        a_lds[k]  = slot ? (row * RAW_S + 4 * cg) : 0;
    }

    // ---- B-stage task geometry (8-wide strips over 34x72 region)
    const int  r0 = tid / 9;
    const int  c0 = (tid - r0 * 9) * 8;
    const bool has1 = tid < (NBTASK - 256);    // 50 threads take a 2nd task
    const int  t1 = tid + 256;
    const int  r1 = t1 / 9;
    const int  c1 = (t1 - r1 * 9) * 8;

    // ---- D/E geometry: thread owns tile row ty, cols xx..xx+7
    const int ty = tid >> 3;
    const int xx = (tid & 7) * 8;

    // ---- register z-pipelines
    float pm0[8], sp0[8], pm1[8], sp1[8];      // erode z-min state per B task
    float t2A[8], t2B[8], t2C[8];              // 2D-max planes z-1, z, z+1
    float rwA[8], rwB[8], rwC[8];              // raw centers z, z+1, z+2
    #pragma unroll
    for (int j = 0; j < 8; ++j) {
        pm0[j] = sp0[j] = pm1[j] = sp1[j] = PINF;
        t2A[j] = t2B[j] = 0.f;
        rwA[j] = rwB[j] = 0.f;
    }

    auto prefetch = [&](int zz, float4 L[3]) {
        const bool zok = (zz >= 0) && (zz < D_);
        const float* plane = vol + (size_t)zz * (H_ * W_);
        #pragma unroll
        for (int k = 0; k < 3; ++k) {
            float4 v = make_float4(PINF, PINF, PINF, PINF);
            if (zok && a_img[k]) v = *(const float4*)(plane + a_off[k]);
            L[k] = v;
        }
    };

    // B task: 2D 3x3 min of raw -> s; e(zz-1) = min(pm, s) (masked); update pipe
    auto btask = [&](int r, int cb, float pm[8], float sp[8], bool zeok) {
        float vm[10];
        {
            const float* p0 = &raw[r][0];
            const float* p1 = &raw[r + 1][0];
            const float* p2 = &raw[r + 2][0];
            int cl = cb - 1; if (cl < 0) cl = 0;
            int cr = cb + 8; if (cr > RAW_W - 1) cr = RAW_W - 1;
            vm[0] = min3f(p0[cl], p1[cl], p2[cl]);
            vm[9] = min3f(p0[cr], p1[cr], p2[cr]);
            float4 q00 = *(const float4*)(p0 + cb);
            float4 q01 = *(const float4*)(p0 + cb + 4);
            float4 q10 = *(const float4*)(p1 + cb);
            float4 q11 = *(const float4*)(p1 + cb + 4);
            float4 q20 = *(const float4*)(p2 + cb);
            float4 q21 = *(const float4*)(p2 + cb + 4);
            vm[1] = min3f(q00.x, q10.x, q20.x);
            vm[2] = min3f(q00.y, q10.y, q20.y);
            vm[3] = min3f(q00.z, q10.z, q20.z);
            vm[4] = min3f(q00.w, q10.w, q20.w);
            vm[5] = min3f(q01.x, q11.x, q21.x);
            vm[6] = min3f(q01.y, q11.y, q21.y);
            vm[7] = min3f(q01.z, q11.z, q21.z);
            vm[8] = min3f(q01.w, q11.w, q21.w);
        }
        float s[8];
        #pragma unroll
        for (int j = 0; j < 8; ++j) s[j] = min3f(vm[j], vm[j + 1], vm[j + 2]);

        const bool rok = zeok && ((unsigned)(h0 - 1 + r) < (unsigned)H_);
        float e[8];
        #pragma unroll
        for (int j = 0; j < 8; ++j) {
            float ev = fminf(pm[j], s[j]);
            bool ok = rok && ((unsigned)(w0 - 4 + cb + j) < (unsigned)W_);
            e[j] = ok ? ev : -PINF;
            pm[j] = fminf(sp[j], s[j]);
            sp[j] = s[j];
        }
        *(float4*)&ebuf[r][cb]     = make_float4(e[0], e[1], e[2], e[3]);
        *(float4*)&ebuf[r][cb + 4] = make_float4(e[4], e[5], e[6], e[7]);
    };

    float4 L[3];
    prefetch(z0 - 2, L);
    const int zzend = z0 + CD + 1;

    for (int zz = z0 - 2; zz <= zzend; ++zz) {
        // ---- A: commit prefetched raw plane zz to LDS, start loading zz+1
        #pragma unroll
        for (int k = 0; k < 3; ++k)
            if (a_slot[k]) *(float4*)(&raw[0][0] + a_lds[k]) = L[k];
        if (zz < zzend) prefetch(zz + 1, L);
        __syncthreads();

        // ---- A2: capture raw centers of plane zz (for output zz-2 later)
        {
            float4 v0 = *(const float4*)&raw[ty + 2][xx + 4];
            float4 v1 = *(const float4*)&raw[ty + 2][xx + 8];
            rwC[0] = v0.x; rwC[1] = v0.y; rwC[2] = v0.z; rwC[3] = v0.w;
            rwC[4] = v1.x; rwC[5] = v1.y; rwC[6] = v1.z; rwC[7] = v1.w;
        }

        // ---- B: s2d(zz) + full erode e(zz-1) -> ebuf
        const int  ze   = zz - 1;
        const bool zeok = (ze >= 0) && (ze < D_);
        btask(r0, c0, pm0, sp0, zeok);
        if (has1) btask(r1, c1, pm1, sp1, zeok);
        __syncthreads();

        // ---- D: 2D 3x3 max of e(zz-1) -> t2C (registers)
        {
            float vm[10];
            const float* p0 = &ebuf[ty][0];
            const float* p1 = &ebuf[ty + 1][0];
            const float* p2 = &ebuf[ty + 2][0];
            vm[0] = max3f(p0[xx + 3], p1[xx + 3], p2[xx + 3]);
            vm[9] = max3f(p0[xx + 12], p1[xx + 12], p2[xx + 12]);
            float4 q00 = *(const float4*)(p0 + xx + 4);
            float4 q01 = *(const float4*)(p0 + xx + 8);
            float4 q10 = *(const float4*)(p1 + xx + 4);
            float4 q11 = *(const float4*)(p1 + xx + 8);
            float4 q20 = *(const float4*)(p2 + xx + 4);
            float4 q21 = *(const float4*)(p2 + xx + 8);
            vm[1] = max3f(q00.x, q10.x, q20.x);
            vm[2] = max3f(q00.y, q10.y, q20.y);
            vm[3] = max3f(q00.z, q10.z, q20.z);
            vm[4] = max3f(q00.w, q10.w, q20.w);
            vm[5] = max3f(q01.x, q11.x, q21.x);
            vm[6] = max3f(q01.y, q11.y, q21.y);
            vm[7] = max3f(q01.z, q11.z, q21.z);
            vm[8] = max3f(q01.w, q11.w, q21.w);
            #pragma unroll
            for (int j = 0; j < 8; ++j) t2C[j] = max3f(vm[j], vm[j + 1], vm[j + 2]);
        }

        // ---- E: output plane z = zz-2: relu(raw - max over t2 planes)
        if (zz >= z0 + 2) {
            const int z = zz - 2;
            float* op = ovol + ((size_t)z * H_ + (h0 + ty)) * W_ + (w0 + xx);
            float o[8];
            #pragma unroll
            for (int j = 0; j < 8; ++j) {
                float opened = max3f(t2A[j], t2B[j], t2C[j]);
                float v = rwA[j] - opened;
                o[j] = v > 0.f ? v : 0.f;
            }
            *(float4*)op       = make_float4(o[0], o[1], o[2], o[3]);
            *(float4*)(op + 4) = make_float4(o[4], o[5], o[6], o[7]);
        }

        // ---- shift register pipelines
        #pragma unroll
        for (int j = 0; j < 8; ++j) {
            t2A[j] = t2B[j]; t2B[j] = t2C[j];
            rwA[j] = rwB[j]; rwB[j] = rwC[j];
        }
    }
}

extern "C" void kernel_launch(void* const* d_in, const int* in_sizes, int n_in,
                              void* d_out, int out_size, void* d_ws, size_t ws_size,
                              hipStream_t stream) {
    const float* img = (const float*)d_in[0];
    float* out = (float*)d_out;

    dim3 grid(W_ / TW, H_ / TH, NB * NCHUNK);   // (4, 8, 32) = 1024 blocks
    dim3 block(256);
    soft_skel_v4<<<grid, block, 0, stream>>>(img, out);
}

// Round 3
// 200.253 us; speedup vs baseline: 2.1751x; 1.1555x over previous
//
#include <hip/hip_runtime.h>
#include <math.h>

// SoftSkeletonize: out = relu(img - dilate3(erode3(img))), (2,1,192,256,256) f32.
// erode = min-pool 3x3x3 (pad +inf), dilate = max-pool 3x3x3 (pad -inf).
//
// v2: z-direction pipelines in REGISTERS (per-position => same thread each
// plane): pmin/sprev carry the erode z-min, t2A/B/C carry the 2D-max planes,
// rwA/B/C carry raw centers. LDS holds only ONE raw plane + ONE eroded plane.
// All LDS access is b128-vectorized (8-wide thread strips), 2 barriers/plane,
// next raw plane software-prefetched into registers during compute.
//
// v3 FAILED: launch_bounds(256,6) forced VGPR 72->40; register state spilled
// (WRITE 98->744MB, dur 74.6->322us).
// v4 FAILED: launch_bounds(256,4) still capped VGPR at 64 (this toolchain
// applies wave32 accounting to the 2nd arg: cap = 512/(2*arg)), mild spill
// (WRITE 98->142MB), dur 112.8us. Calibration: arg=3 -> cap ~85 (72 used,
// no spill); arg>=4 -> spill. DO NOT raise the 2nd arg on this kernel.
//
// v5: keep launch_bounds(256,3) (VGPR=72, zero spill). At 72 VGPRs the HW
// residency limit is 16 waves/CU = 4 blocks (m69 steps at 64/128), LDS allows
// 7 -> v2 was GRID-limited at 3 blocks/CU (768 blocks). Supply the 4th
// resident block via the grid instead: CD=12 -> 1024 blocks = exactly 4/CU.
// z-halo tax 16/12 = 1.33x (fetch ~117->~125MB) vs +33% concurrency.

#define D_ 192
#define H_ 256
#define W_ 256
#define NB 2
#define TH 32
#define TW 64
#define CD 12
#define NCHUNK (D_ / CD)      // 16

#define RAW_H (TH + 4)        // 36 rows  <-> gh = h0-2 .. h0+33
#define RAW_W (TW + 8)        // 72 cols  <-> gw = w0-4 .. w0+67
#define RAW_S 76              // padded stride (76 mod 32 = 12 -> bank spread)
#define EB_H  (TH + 2)        // 34 rows  <-> gh = h0-1 .. h0+32
#define EB_W  (TW + 8)        // 72 cols  <-> gw = w0-4 .. w0+67
#define EB_S  76

#define NRAWF4 (RAW_H * (RAW_W / 4))   // 648 float4 cells
#define NBTASK (EB_H * (EB_W / 8))     // 306 8-wide tasks

__device__ __forceinline__ float min3f(float a, float b, float c) {
    return fminf(fminf(a, b), c);
}
__device__ __forceinline__ float max3f(float a, float b, float c) {
    return fmaxf(fmaxf(a, b), c);
}

__global__ __launch_bounds__(256, 3)
void soft_skel_v5(const float* __restrict__ img, float* __restrict__ out) {
    __shared__ __align__(16) float raw[RAW_H][RAW_S];
    __shared__ __align__(16) float ebuf[EB_H][EB_S];

    const int tid = threadIdx.x;
    const int w0 = blockIdx.x * TW;
    const int h0 = blockIdx.y * TH;
    const int n  = blockIdx.z / NCHUNK;
    const int ch = blockIdx.z - n * NCHUNK;
    const int z0 = ch * CD;

    const float* vol  = img + (size_t)n * (D_ * H_ * W_);
    float*       ovol = out + (size_t)n * (D_ * H_ * W_);

    const float PINF = INFINITY;

    // ---- A-stage per-thread geometry: 3 float4 slots cover the 36x72 region
    bool a_slot[3], a_img[3];
    int  a_lds[3], a_off[3];
    #pragma unroll
    for (int k = 0; k < 3; ++k) {
        int idx = tid + 256 * k;
        bool slot = idx < NRAWF4;
        int row = idx / (RAW_W / 4);           // /18
        int cg  = idx - row * (RAW_W / 4);
        int gh = h0 - 2 + row;
        int gw = w0 - 4 + 4 * cg;
        a_slot[k] = slot;
        a_img[k]  = slot && (gh >= 0) && (gh < H_) && (gw >= 0) && (gw <= W_ - 4);
        a_off[k]  = gh * W_ + gw;
        a_lds[k]  = slot ? (row * RAW_S + 4 * cg) : 0;
    }

    // ---- B-stage task geometry (8-wide strips over 34x72 region)
    const int  r0 = tid / 9;
    const int  c0 = (tid - r0 * 9) * 8;
    const bool has1 = tid < (NBTASK - 256);    // 50 threads take a 2nd task
    const int  t1 = tid + 256;
    const int  r1 = t1 / 9;
    const int  c1 = (t1 - r1 * 9) * 8;

    // ---- D/E geometry: thread owns tile row ty, cols xx..xx+7
    const int ty = tid >> 3;
    const int xx = (tid & 7) * 8;

    // ---- register z-pipelines
    float pm0[8], sp0[8], pm1[8], sp1[8];      // erode z-min state per B task
    float t2A[8], t2B[8], t2C[8];              // 2D-max planes z-1, z, z+1
    float rwA[8], rwB[8], rwC[8];              // raw centers z, z+1, z+2
    #pragma unroll
    for (int j = 0; j < 8; ++j) {
        pm0[j] = sp0[j] = pm1[j] = sp1[j] = PINF;
        t2A[j] = t2B[j] = 0.f;
        rwA[j] = rwB[j] = 0.f;
    }

    auto prefetch = [&](int zz, float4 L[3]) {
        const bool zok = (zz >= 0) && (zz < D_);
        const float* plane = vol + (size_t)zz * (H_ * W_);
        #pragma unroll
        for (int k = 0; k < 3; ++k) {
            float4 v = make_float4(PINF, PINF, PINF, PINF);
            if (zok && a_img[k]) v = *(const float4*)(plane + a_off[k]);
            L[k] = v;
        }
    };

    // B task: 2D 3x3 min of raw -> s; e(zz-1) = min(pm, s) (masked); update pipe
    auto btask = [&](int r, int cb, float pm[8], float sp[8], bool zeok) {
        float vm[10];
        {
            const float* p0 = &raw[r][0];
            const float* p1 = &raw[r + 1][0];
            const float* p2 = &raw[r + 2][0];
            int cl = cb - 1; if (cl < 0) cl = 0;
            int cr = cb + 8; if (cr > RAW_W - 1) cr = RAW_W - 1;
            vm[0] = min3f(p0[cl], p1[cl], p2[cl]);
            vm[9] = min3f(p0[cr], p1[cr], p2[cr]);
            float4 q00 = *(const float4*)(p0 + cb);
            float4 q01 = *(const float4*)(p0 + cb + 4);
            float4 q10 = *(const float4*)(p1 + cb);
            float4 q11 = *(const float4*)(p1 + cb + 4);
            float4 q20 = *(const float4*)(p2 + cb);
            float4 q21 = *(const float4*)(p2 + cb + 4);
            vm[1] = min3f(q00.x, q10.x, q20.x);
            vm[2] = min3f(q00.y, q10.y, q20.y);
            vm[3] = min3f(q00.z, q10.z, q20.z);
            vm[4] = min3f(q00.w, q10.w, q20.w);
            vm[5] = min3f(q01.x, q11.x, q21.x);
            vm[6] = min3f(q01.y, q11.y, q21.y);
            vm[7] = min3f(q01.z, q11.z, q21.z);
            vm[8] = min3f(q01.w, q11.w, q21.w);
        }
        float s[8];
        #pragma unroll
        for (int j = 0; j < 8; ++j) s[j] = min3f(vm[j], vm[j + 1], vm[j + 2]);

        const bool rok = zeok && ((unsigned)(h0 - 1 + r) < (unsigned)H_);
        float e[8];
        #pragma unroll
        for (int j = 0; j < 8; ++j) {
            float ev = fminf(pm[j], s[j]);
            bool ok = rok && ((unsigned)(w0 - 4 + cb + j) < (unsigned)W_);
            e[j] = ok ? ev : -PINF;
            pm[j] = fminf(sp[j], s[j]);
            sp[j] = s[j];
        }
        *(float4*)&ebuf[r][cb]     = make_float4(e[0], e[1], e[2], e[3]);
        *(float4*)&ebuf[r][cb + 4] = make_float4(e[4], e[5], e[6], e[7]);
    };

    float4 L[3];
    prefetch(z0 - 2, L);
    const int zzend = z0 + CD + 1;

    for (int zz = z0 - 2; zz <= zzend; ++zz) {
        // ---- A: commit prefetched raw plane zz to LDS, start loading zz+1
        #pragma unroll
        for (int k = 0; k < 3; ++k)
            if (a_slot[k]) *(float4*)(&raw[0][0] + a_lds[k]) = L[k];
        if (zz < zzend) prefetch(zz + 1, L);
        __syncthreads();

        // ---- A2: capture raw centers of plane zz (for output zz-2 later)
        {
            float4 v0 = *(const float4*)&raw[ty + 2][xx + 4];
            float4 v1 = *(const float4*)&raw[ty + 2][xx + 8];
            rwC[0] = v0.x; rwC[1] = v0.y; rwC[2] = v0.z; rwC[3] = v0.w;
            rwC[4] = v1.x; rwC[5] = v1.y; rwC[6] = v1.z; rwC[7] = v1.w;
        }

        // ---- B: s2d(zz) + full erode e(zz-1) -> ebuf
        const int  ze   = zz - 1;
        const bool zeok = (ze >= 0) && (ze < D_);
        btask(r0, c0, pm0, sp0, zeok);
        if (has1) btask(r1, c1, pm1, sp1, zeok);
        __syncthreads();

        // ---- D: 2D 3x3 max of e(zz-1) -> t2C (registers)
        {
            float vm[10];
            const float* p0 = &ebuf[ty][0];
            const float* p1 = &ebuf[ty + 1][0];
            const float* p2 = &ebuf[ty + 2][0];
            vm[0] = max3f(p0[xx + 3], p1[xx + 3], p2[xx + 3]);
            vm[9] = max3f(p0[xx + 12], p1[xx + 12], p2[xx + 12]);
            float4 q00 = *(const float4*)(p0 + xx + 4);
            float4 q01 = *(const float4*)(p0 + xx + 8);
            float4 q10 = *(const float4*)(p1 + xx + 4);
            float4 q11 = *(const float4*)(p1 + xx + 8);
            float4 q20 = *(const float4*)(p2 + xx + 4);
            float4 q21 = *(const float4*)(p2 + xx + 8);
            vm[1] = max3f(q00.x, q10.x, q20.x);
            vm[2] = max3f(q00.y, q10.y, q20.y);
            vm[3] = max3f(q00.z, q10.z, q20.z);
            vm[4] = max3f(q00.w, q10.w, q20.w);
            vm[5] = max3f(q01.x, q11.x, q21.x);
            vm[6] = max3f(q01.y, q11.y, q21.y);
            vm[7] = max3f(q01.z, q11.z, q21.z);
            vm[8] = max3f(q01.w, q11.w, q21.w);
            #pragma unroll
            for (int j = 0; j < 8; ++j) t2C[j] = max3f(vm[j], vm[j + 1], vm[j + 2]);
        }

        // ---- E: output plane z = zz-2: relu(raw - max over t2 planes)
        if (zz >= z0 + 2) {
            const int z = zz - 2;
            float* op = ovol + ((size_t)z * H_ + (h0 + ty)) * W_ + (w0 + xx);
            float o[8];
            #pragma unroll
            for (int j = 0; j < 8; ++j) {
                float opened = max3f(t2A[j], t2B[j], t2C[j]);
                float v = rwA[j] - opened;
                o[j] = v > 0.f ? v : 0.f;
            }
            *(float4*)op       = make_float4(o[0], o[1], o[2], o[3]);
            *(float4*)(op + 4) = make_float4(o[4], o[5], o[6], o[7]);
        }

        // ---- shift register pipelines
        #pragma unroll
        for (int j = 0; j < 8; ++j) {
            t2A[j] = t2B[j]; t2B[j] = t2C[j];
            rwA[j] = rwB[j]; rwB[j] = rwC[j];
        }
    }
}

extern "C" void kernel_launch(void* const* d_in, const int* in_sizes, int n_in,
                              void* d_out, int out_size, void* d_ws, size_t ws_size,
                              hipStream_t stream) {
    const float* img = (const float*)d_in[0];
    float* out = (float*)d_out;

    dim3 grid(W_ / TW, H_ / TH, NB * NCHUNK);   // (4, 8, 32) = 1024 blocks
    dim3 block(256);
    soft_skel_v5<<<grid, block, 0, stream>>>(img, out);
}

// Round 4
// 195.741 us; speedup vs baseline: 2.2252x; 1.0231x over previous
//
#include <hip/hip_runtime.h>
#include <math.h>

// SoftSkeletonize: out = relu(img - dilate3(erode3(img))), (2,1,192,256,256) f32.
// erode = min-pool 3x3x3 (pad +inf), dilate = max-pool 3x3x3 (pad -inf).
//
// v2 (74.6us/dispatch): z-pipelines in registers, 1 raw + 1 ebuf plane in LDS,
// b128-vectorized, 2 barriers/plane, register prefetch. PROVEN BEST CONFIG:
// CD=16 (768 blocks), launch_bounds(256,3), VGPR=72 no spill.
//
// v3/v4 FAILED: raising launch_bounds 2nd arg (6,4) collapsed VGPR (40/64)
// -> scratch spill (WRITE 98->744/142MB). arg=3 is the no-spill point.
// v5 FAILED: CD=12 (1024 blocks = 4/CU) did NOT raise measured occupancy
// (27->22.5%) and per-iter cost rose 5%. Lesson: kernel is NOT wave-starved;
// per-CU throughput is LDS-pipe-bound (~70% busy incl. conflicts).
//
// v6: attack the conflicts. SQ_LDS_BANK_CONFLICT = 1141 cyc/block-iter ~=
// the base LDS time itself. Cause: scalar edge reads (B: col cb-1/cb+8,
// D: col xx+3/xx+12). All LDS addrs here are float4-aligned with stride
// 76 == 12 mod 32 (mult of 4) -> a wave64 scalar read hits only 8 of 32
// banks, 8-deep distinct addrs = 8-way conflict (m136: ~3x). The b128s are
// fine (consecutive rows fall in complementary bank groups).
// Fix: neighbor lane ALREADY holds the adjacent column's vertical min/max
// -> __shfl_up/__shfl_down replace all full-wave scalar edge reads;
// 1-8 edge lanes/wave use predicated scalar fallbacks (conflict-free).
// Also: raw-center capture (rwC) moved from LDS re-read to 2 global float4
// loads (L2-hot: plane tiles ~1MB/XCD) -> -8KB/iter off the LDS pipe.

#define D_ 192
#define H_ 256
#define W_ 256
#define NB 2
#define TH 32
#define TW 64
#define CD 16
#define NCHUNK (D_ / CD)      // 12

#define RAW_H (TH + 4)        // 36 rows  <-> gh = h0-2 .. h0+33
#define RAW_W (TW + 8)        // 72 cols  <-> gw = w0-4 .. w0+67
#define RAW_S 76              // padded stride (76 mod 32 = 12 -> bank spread)
#define EB_H  (TH + 2)        // 34 rows  <-> gh = h0-1 .. h0+32
#define EB_W  (TW + 8)        // 72 cols  <-> gw = w0-4 .. w0+67
#define EB_S  76

#define NRAWF4 (RAW_H * (RAW_W / 4))   // 648 float4 cells
#define NBTASK (EB_H * (EB_W / 8))     // 306 8-wide tasks

__device__ __forceinline__ float min3f(float a, float b, float c) {
    return fminf(fminf(a, b), c);
}
__device__ __forceinline__ float max3f(float a, float b, float c) {
    return fmaxf(fmaxf(a, b), c);
}

__global__ __launch_bounds__(256, 3)
void soft_skel_v6(const float* __restrict__ img, float* __restrict__ out) {
    __shared__ __align__(16) float raw[RAW_H][RAW_S];
    __shared__ __align__(16) float ebuf[EB_H][EB_S];

    const int tid  = threadIdx.x;
    const int lane = tid & 63;
    const int w0 = blockIdx.x * TW;
    const int h0 = blockIdx.y * TH;
    const int n  = blockIdx.z / NCHUNK;
    const int ch = blockIdx.z - n * NCHUNK;
    const int z0 = ch * CD;

    const float* vol  = img + (size_t)n * (D_ * H_ * W_);
    float*       ovol = out + (size_t)n * (D_ * H_ * W_);

    const float PINF = INFINITY;

    // ---- A-stage per-thread geometry: 3 float4 slots cover the 36x72 region
    bool a_slot[3], a_img[3];
    int  a_lds[3], a_off[3];
    #pragma unroll
    for (int k = 0; k < 3; ++k) {
        int idx = tid + 256 * k;
        bool slot = idx < NRAWF4;
        int row = idx / (RAW_W / 4);           // /18
        int cg  = idx - row * (RAW_W / 4);
        int gh = h0 - 2 + row;
        int gw = w0 - 4 + 4 * cg;
        a_slot[k] = slot;
        a_img[k]  = slot && (gh >= 0) && (gh < H_) && (gw >= 0) && (gw <= W_ - 4);
        a_off[k]  = gh * W_ + gw;
        a_lds[k]  = slot ? (row * RAW_S + 4 * cg) : 0;
    }

    // ---- B-stage task geometry (8-wide strips over 34x72 region)
    const int  r0 = tid / 9;
    const int  c0 = (tid - r0 * 9) * 8;
    const bool has1 = tid < (NBTASK - 256);    // 50 threads take a 2nd task
    const int  t1 = tid + 256;
    const int  r1 = t1 / 9;
    const int  c1 = (t1 - r1 * 9) * 8;

    // ---- D/E geometry: thread owns tile row ty, cols xx..xx+7
    const int ty = tid >> 3;
    const int cx = tid & 7;
    const int xx = cx * 8;

    // ---- register z-pipelines
    float pm0[8], sp0[8], pm1[8], sp1[8];      // erode z-min state per B task
    float t2A[8], t2B[8], t2C[8];              // 2D-max planes z-1, z, z+1
    float rwA[8], rwB[8], rwC[8];              // raw centers z, z+1, z+2
    #pragma unroll
    for (int j = 0; j < 8; ++j) {
        pm0[j] = sp0[j] = pm1[j] = sp1[j] = PINF;
        t2A[j] = t2B[j] = 0.f;
        rwA[j] = rwB[j] = 0.f;
    }

    auto prefetch = [&](int zz, float4 L[3]) {
        const bool zok = (zz >= 0) && (zz < D_);
        const float* plane = vol + (size_t)zz * (H_ * W_);
        #pragma unroll
        for (int k = 0; k < 3; ++k) {
            float4 v = make_float4(PINF, PINF, PINF, PINF);
            if (zok && a_img[k]) v = *(const float4*)(plane + a_off[k]);
            L[k] = v;
        }
    };

    // B task: 2D 3x3 min of raw -> s; e(zz-1) = min(pm, s) (masked); update pipe.
    // Edge columns come from neighbor lanes via shuffle (consecutive tid ==
    // consecutive task). Wave-boundary lanes use predicated scalar fallbacks.
    auto btask = [&](int r, int cb, float pm[8], float sp[8], bool zeok) {
        float4 q00 = *(const float4*)(&raw[r][cb]);
        float4 q01 = *(const float4*)(&raw[r][cb + 4]);
        float4 q10 = *(const float4*)(&raw[r + 1][cb]);
        float4 q11 = *(const float4*)(&raw[r + 1][cb + 4]);
        float4 q20 = *(const float4*)(&raw[r + 2][cb]);
        float4 q21 = *(const float4*)(&raw[r + 2][cb + 4]);
        float v[8];
        v[0] = min3f(q00.x, q10.x, q20.x);
        v[1] = min3f(q00.y, q10.y, q20.y);
        v[2] = min3f(q00.z, q10.z, q20.z);
        v[3] = min3f(q00.w, q10.w, q20.w);
        v[4] = min3f(q01.x, q11.x, q21.x);
        v[5] = min3f(q01.y, q11.y, q21.y);
        v[6] = min3f(q01.z, q11.z, q21.z);
        v[7] = min3f(q01.w, q11.w, q21.w);

        // edges: neighbor task's boundary column via intra-wave shuffle
        float vL = __shfl_up(v[7], 1);     // = neighbor's col cb-1
        float vR = __shfl_down(v[0], 1);   // = neighbor's col cb+8
        if (lane == 0) {                   // no in-wave left neighbor
            int cl = cb - 1; if (cl < 0) cl = 0;
            vL = min3f(raw[r][cl], raw[r + 1][cl], raw[r + 2][cl]);
        }
        if (lane == 63) {                  // no in-wave right neighbor
            int cr = cb + 8; if (cr > RAW_W - 1) cr = RAW_W - 1;
            vR = min3f(raw[r][cr], raw[r + 1][cr], raw[r + 2][cr]);
        }

        float s[8];
        s[0] = min3f(vL, v[0], v[1]);
        #pragma unroll
        for (int j = 1; j < 7; ++j) s[j] = min3f(v[j - 1], v[j], v[j + 1]);
        s[7] = min3f(v[6], v[7], vR);

        const bool rok = zeok && ((unsigned)(h0 - 1 + r) < (unsigned)H_);
        float e[8];
        #pragma unroll
        for (int j = 0; j < 8; ++j) {
            float ev = fminf(pm[j], s[j]);
            bool ok = rok && ((unsigned)(w0 - 4 + cb + j) < (unsigned)W_);
            e[j] = ok ? ev : -PINF;
            pm[j] = fminf(sp[j], s[j]);
            sp[j] = s[j];
        }
        *(float4*)&ebuf[r][cb]     = make_float4(e[0], e[1], e[2], e[3]);
        *(float4*)&ebuf[r][cb + 4] = make_float4(e[4], e[5], e[6], e[7]);
    };

    float4 L[3];
    prefetch(z0 - 2, L);
    const int zzend = z0 + CD + 1;

    for (int zz = z0 - 2; zz <= zzend; ++zz) {
        // ---- A: commit prefetched raw plane zz to LDS, start loading zz+1
        #pragma unroll
        for (int k = 0; k < 3; ++k)
            if (a_slot[k]) *(float4*)(&raw[0][0] + a_lds[k]) = L[k];
        if (zz < zzend) prefetch(zz + 1, L);
        __syncthreads();

        // ---- A2: raw centers of plane zz from GLOBAL (L2-hot; off the LDS
        // pipe). Issued here, drained by the pre-barrier waitcnt after B.
        float4 c0v, c1v;
        const bool zcok = (zz >= 0) && (zz < D_);
        if (zcok) {
            const float* cp = vol + ((size_t)zz * H_ + (h0 + ty)) * W_ + (w0 + xx);
            c0v = *(const float4*)cp;
            c1v = *(const float4*)(cp + 4);
        } else {
            c0v = c1v = make_float4(0.f, 0.f, 0.f, 0.f);  // unused downstream
        }

        // ---- B: s2d(zz) + full erode e(zz-1) -> ebuf
        const int  ze   = zz - 1;
        const bool zeok = (ze >= 0) && (ze < D_);
        btask(r0, c0, pm0, sp0, zeok);
        if (has1) btask(r1, c1, pm1, sp1, zeok);

        // commit centers into the register pipeline
        rwC[0] = c0v.x; rwC[1] = c0v.y; rwC[2] = c0v.z; rwC[3] = c0v.w;
        rwC[4] = c1v.x; rwC[5] = c1v.y; rwC[6] = c1v.z; rwC[7] = c1v.w;
        __syncthreads();

        // ---- D: 2D 3x3 max of e(zz-1) -> t2C (registers)
        {
            const float* p0 = &ebuf[ty][0];
            const float* p1 = &ebuf[ty + 1][0];
            const float* p2 = &ebuf[ty + 2][0];
            float4 q00 = *(const float4*)(p0 + xx + 4);
            float4 q01 = *(const float4*)(p0 + xx + 8);
            float4 q10 = *(const float4*)(p1 + xx + 4);
            float4 q11 = *(const float4*)(p1 + xx + 8);
            float4 q20 = *(const float4*)(p2 + xx + 4);
            float4 q21 = *(const float4*)(p2 + xx + 8);
            float t[8];
            t[0] = max3f(q00.x, q10.x, q20.x);
            t[1] = max3f(q00.y, q10.y, q20.y);
            t[2] = max3f(q00.z, q10.z, q20.z);
            t[3] = max3f(q00.w, q10.w, q20.w);
            t[4] = max3f(q01.x, q11.x, q21.x);
            t[5] = max3f(q01.y, q11.y, q21.y);
            t[6] = max3f(q01.z, q11.z, q21.z);
            t[7] = max3f(q01.w, q11.w, q21.w);

            float tL = __shfl_up(t[7], 1);     // = col xx+3
            float tR = __shfl_down(t[0], 1);   // = col xx+12
            if (cx == 0) {                     // left tile edge: col 3
                tL = max3f(p0[xx + 3], p1[xx + 3], p2[xx + 3]);
            }
            if (cx == 7) {                     // right tile edge: col 68
                tR = max3f(p0[xx + 12], p1[xx + 12], p2[xx + 12]);
            }
            t2C[0] = max3f(tL, t[0], t[1]);
            #pragma unroll
            for (int j = 1; j < 7; ++j) t2C[j] = max3f(t[j - 1], t[j], t[j + 1]);
            t2C[7] = max3f(t[6], t[7], tR);
        }

        // ---- E: output plane z = zz-2: relu(raw - max over t2 planes)
        if (zz >= z0 + 2) {
            const int z = zz - 2;
            float* op = ovol + ((size_t)z * H_ + (h0 + ty)) * W_ + (w0 + xx);
            float o[8];
            #pragma unroll
            for (int j = 0; j < 8; ++j) {
                float opened = max3f(t2A[j], t2B[j], t2C[j]);
                float v = rwA[j] - opened;
                o[j] = v > 0.f ? v : 0.f;
            }
            *(float4*)op       = make_float4(o[0], o[1], o[2], o[3]);
            *(float4*)(op + 4) = make_float4(o[4], o[5], o[6], o[7]);
        }

        // ---- shift register pipelines
        #pragma unroll
        for (int j = 0; j < 8; ++j) {
            t2A[j] = t2B[j]; t2B[j] = t2C[j];
            rwA[j] = rwB[j]; rwB[j] = rwC[j];
        }
    }
}

extern "C" void kernel_launch(void* const* d_in, const int* in_sizes, int n_in,
                              void* d_out, int out_size, void* d_ws, size_t ws_size,
                              hipStream_t stream) {
    const float* img = (const float*)d_in[0];
    float* out = (float*)d_out;

    dim3 grid(W_ / TW, H_ / TH, NB * NCHUNK);   // (4, 8, 24) = 768 blocks
    dim3 block(256);
    soft_skel_v6<<<grid, block, 0, stream>>>(img, out);
}

// Round 5
// 194.033 us; speedup vs baseline: 2.2448x; 1.0088x over previous
//
#include <hip/hip_runtime.h>
#include <math.h>

// SoftSkeletonize: out = relu(img - dilate3(erode3(img))), (2,1,192,256,256) f32.
// erode = min-pool 3x3x3 (pad +inf), dilate = max-pool 3x3x3 (pad -inf).
//
// v2 (74.6us/dispatch): z-pipelines in registers, 1 raw + 1 ebuf plane in LDS,
// b128-vectorized, 2 barriers/plane, register prefetch. CD=16 (768 blocks),
// launch_bounds(256,3), VGPR=72 no spill.
// v3/v4 FAILED: raising launch_bounds 2nd arg collapsed VGPR -> scratch spill.
// v5 FAILED: 4 blocks/CU via CD=12: no occupancy gain, +halo tax. Not wave-starved.
// v6 NEUTRAL: shuffle edge-fix cut SQ_LDS_BANK_CONFLICT 1.87e7->4.87e6 but dur
// 74.6->77.5us: conflicts weren't critical-path, and global-center A2 added
// +18MB HBM fetch (~+6us). Lesson: no pipe >50% busy -> phase/latency-bound.
//
// v7: kill the exposed-latency structure. hipcc drains vmcnt(0)+lgkmcnt(0)
// before every s_barrier; v2/v6 issue the global prefetch RIGHT BEFORE a
// barrier (full load latency exposed per iter) and had 2 barriers/plane.
// Changes:
//  - double-buffer raw AND ebuf (42.6KB LDS, still 3 blocks/CU = all the
//    grid gives): D reads ebuf[prev] = t2(e(zz-2)) -> B->D barrier gone,
//    ONE barrier per plane. Output lags one more plane (z = zz-3, 21 iters).
//  - prefetch issued just AFTER the barrier: loads have the whole B+D+E
//    phase (~1500cyc) to land; pre-barrier vmcnt drain finds nothing.
//  - A2 centers back to LDS (v6's global read cost +18MB fetch), read from
//    raw[prev] PRE-barrier (other buffer: race-free; keeps rw pipe 3-deep).
//  - keep v6 shuffle edge-fix (conflicts stay ~4x down).

#define D_ 192
#define H_ 256
#define W_ 256
#define NB 2
#define TH 32
#define TW 64
#define CD 16
#define NCHUNK (D_ / CD)      // 12

#define RAW_H (TH + 4)        // 36 rows  <-> gh = h0-2 .. h0+33
#define RAW_W (TW + 8)        // 72 cols  <-> gw = w0-4 .. w0+67
#define RAW_S 76              // padded stride
#define EB_H  (TH + 2)        // 34 rows  <-> gh = h0-1 .. h0+32
#define EB_W  (TW + 8)        // 72 cols
#define EB_S  76

#define NRAWF4 (RAW_H * (RAW_W / 4))   // 648 float4 cells
#define NBTASK (EB_H * (EB_W / 8))     // 306 8-wide tasks

__device__ __forceinline__ float min3f(float a, float b, float c) {
    return fminf(fminf(a, b), c);
}
__device__ __forceinline__ float max3f(float a, float b, float c) {
    return fmaxf(fmaxf(a, b), c);
}

__global__ __launch_bounds__(256, 3)
void soft_skel_v7(const float* __restrict__ img, float* __restrict__ out) {
    __shared__ __align__(16) float raw[2][RAW_H][RAW_S];
    __shared__ __align__(16) float ebuf[2][EB_H][EB_S];

    const int tid  = threadIdx.x;
    const int lane = tid & 63;
    const int w0 = blockIdx.x * TW;
    const int h0 = blockIdx.y * TH;
    const int n  = blockIdx.z / NCHUNK;
    const int ch = blockIdx.z - n * NCHUNK;
    const int z0 = ch * CD;

    const float* vol  = img + (size_t)n * (D_ * H_ * W_);
    float*       ovol = out + (size_t)n * (D_ * H_ * W_);

    const float PINF = INFINITY;

    // ---- A-stage per-thread geometry: 3 float4 slots cover the 36x72 region
    bool a_slot[3], a_img[3];
    int  a_lds[3], a_off[3];
    #pragma unroll
    for (int k = 0; k < 3; ++k) {
        int idx = tid + 256 * k;
        bool slot = idx < NRAWF4;
        int row = idx / (RAW_W / 4);           // /18
        int cg  = idx - row * (RAW_W / 4);
        int gh = h0 - 2 + row;
        int gw = w0 - 4 + 4 * cg;
        a_slot[k] = slot;
        a_img[k]  = slot && (gh >= 0) && (gh < H_) && (gw >= 0) && (gw <= W_ - 4);
        a_off[k]  = gh * W_ + gw;
        a_lds[k]  = slot ? (row * RAW_S + 4 * cg) : 0;
    }

    // ---- B-stage task geometry (8-wide strips over 34x72 region)
    const int  r0 = tid / 9;
    const int  c0 = (tid - r0 * 9) * 8;
    const bool has1 = tid < (NBTASK - 256);    // 50 threads take a 2nd task
    const int  t1 = tid + 256;
    const int  r1 = t1 / 9;
    const int  c1 = (t1 - r1 * 9) * 8;

    // ---- D/E geometry: thread owns tile row ty, cols xx..xx+7
    const int ty = tid >> 3;
    const int cx = tid & 7;
    const int xx = cx * 8;

    // ---- register z-pipelines
    float pm0[8], sp0[8], pm1[8], sp1[8];      // erode z-min state per B task
    float t2A[8], t2B[8], t2C[8];              // 2D-max planes of e(zz-4..zz-2)
    float rw0[8], rw1[8], rw2[8];              // raw centers zz-3, zz-2, zz-1
    #pragma unroll
    for (int j = 0; j < 8; ++j) {
        pm0[j] = sp0[j] = pm1[j] = sp1[j] = PINF;
        t2A[j] = t2B[j] = 0.f;
        rw0[j] = rw1[j] = 0.f;
    }

    auto prefetch = [&](int zz, float4 L[3]) {
        const bool zok = (zz >= 0) && (zz < D_);
        const float* plane = vol + (size_t)zz * (H_ * W_);
        #pragma unroll
        for (int k = 0; k < 3; ++k) {
            float4 v = make_float4(PINF, PINF, PINF, PINF);
            if (zok && a_img[k]) v = *(const float4*)(plane + a_off[k]);
            L[k] = v;
        }
    };

    // B task: 2D 3x3 min of rb -> s; e(zz-1) = min(pm, s) (masked) -> eb.
    // Edge columns via intra-wave shuffle; boundary lanes use scalar fallback.
    auto btask = [&](const float (*rb)[RAW_S], float (*eb)[EB_S],
                     int r, int cb, float pm[8], float sp[8], bool zeok) {
        float4 q00 = *(const float4*)(&rb[r][cb]);
        float4 q01 = *(const float4*)(&rb[r][cb + 4]);
        float4 q10 = *(const float4*)(&rb[r + 1][cb]);
        float4 q11 = *(const float4*)(&rb[r + 1][cb + 4]);
        float4 q20 = *(const float4*)(&rb[r + 2][cb]);
        float4 q21 = *(const float4*)(&rb[r + 2][cb + 4]);
        float v[8];
        v[0] = min3f(q00.x, q10.x, q20.x);
        v[1] = min3f(q00.y, q10.y, q20.y);
        v[2] = min3f(q00.z, q10.z, q20.z);
        v[3] = min3f(q00.w, q10.w, q20.w);
        v[4] = min3f(q01.x, q11.x, q21.x);
        v[5] = min3f(q01.y, q11.y, q21.y);
        v[6] = min3f(q01.z, q11.z, q21.z);
        v[7] = min3f(q01.w, q11.w, q21.w);

        float vL = __shfl_up(v[7], 1);     // neighbor task's col cb-1
        float vR = __shfl_down(v[0], 1);   // neighbor task's col cb+8
        if (lane == 0) {
            int cl = cb - 1; if (cl < 0) cl = 0;
            vL = min3f(rb[r][cl], rb[r + 1][cl], rb[r + 2][cl]);
        }
        if (lane == 63) {
            int cr = cb + 8; if (cr > RAW_W - 1) cr = RAW_W - 1;
            vR = min3f(rb[r][cr], rb[r + 1][cr], rb[r + 2][cr]);
        }

        float s[8];
        s[0] = min3f(vL, v[0], v[1]);
        #pragma unroll
        for (int j = 1; j < 7; ++j) s[j] = min3f(v[j - 1], v[j], v[j + 1]);
        s[7] = min3f(v[6], v[7], vR);

        const bool rok = zeok && ((unsigned)(h0 - 1 + r) < (unsigned)H_);
        float e[8];
        #pragma unroll
        for (int j = 0; j < 8; ++j) {
            float ev = fminf(pm[j], s[j]);
            bool ok = rok && ((unsigned)(w0 - 4 + cb + j) < (unsigned)W_);
            e[j] = ok ? ev : -PINF;
            pm[j] = fminf(sp[j], s[j]);
            sp[j] = s[j];
        }
        *(float4*)&eb[r][cb]     = make_float4(e[0], e[1], e[2], e[3]);
        *(float4*)&eb[r][cb + 4] = make_float4(e[4], e[5], e[6], e[7]);
    };

    float4 L[3];
    prefetch(z0 - 2, L);
    const int zzend = z0 + CD + 2;
    int cur = 0;

    for (int zz = z0 - 2; zz <= zzend; ++zz) {
        float (*rb)[RAW_S]        = raw[cur];
        const float (*rbp)[RAW_S] = raw[cur ^ 1];
        float (*eb)[EB_S]         = ebuf[cur];
        const float (*ebp)[EB_S]  = ebuf[cur ^ 1];

        // ---- A: commit prefetched raw plane zz into raw[cur]
        #pragma unroll
        for (int k = 0; k < 3; ++k)
            if (a_slot[k]) *(float4*)(&rb[0][0] + a_lds[k]) = L[k];

        // ---- A2 (pre-barrier, other buffer => race-free): centers of plane
        // zz-1 from raw[prev]; committed to rw2 after the barrier.
        float4 c0v = *(const float4*)&rbp[ty + 2][xx + 4];
        float4 c1v = *(const float4*)&rbp[ty + 2][xx + 8];

        __syncthreads();   // the ONLY barrier per plane

        // ---- prefetch next plane NOW: in flight across B+D+E, consumed at
        // next iter's A-commit (not squeezed against a barrier drain).
        if (zz < zzend) prefetch(zz + 1, L);

        rw2[0] = c0v.x; rw2[1] = c0v.y; rw2[2] = c0v.z; rw2[3] = c0v.w;
        rw2[4] = c1v.x; rw2[5] = c1v.y; rw2[6] = c1v.z; rw2[7] = c1v.w;

        // ---- B: s2d(zz) + full erode e(zz-1) -> ebuf[cur]
        const int  ze   = zz - 1;
        const bool zeok = (ze >= 0) && (ze < D_);
        btask(rb, eb, r0, c0, pm0, sp0, zeok);
        if (has1) btask(rb, eb, r1, c1, pm1, sp1, zeok);

        // ---- D: 2D 3x3 max of e(zz-2) from ebuf[prev] -> t2C
        {
            const float* p0 = &ebp[ty][0];
            const float* p1 = &ebp[ty + 1][0];
            const float* p2 = &ebp[ty + 2][0];
            float4 q00 = *(const float4*)(p0 + xx + 4);
            float4 q01 = *(const float4*)(p0 + xx + 8);
            float4 q10 = *(const float4*)(p1 + xx + 4);
            float4 q11 = *(const float4*)(p1 + xx + 8);
            float4 q20 = *(const float4*)(p2 + xx + 4);
            float4 q21 = *(const float4*)(p2 + xx + 8);
            float t[8];
            t[0] = max3f(q00.x, q10.x, q20.x);
            t[1] = max3f(q00.y, q10.y, q20.y);
            t[2] = max3f(q00.z, q10.z, q20.z);
            t[3] = max3f(q00.w, q10.w, q20.w);
            t[4] = max3f(q01.x, q11.x, q21.x);
            t[5] = max3f(q01.y, q11.y, q21.y);
            t[6] = max3f(q01.z, q11.z, q21.z);
            t[7] = max3f(q01.w, q11.w, q21.w);

            float tL = __shfl_up(t[7], 1);     // col xx+3
            float tR = __shfl_down(t[0], 1);   // col xx+12
            if (cx == 0) {
                tL = max3f(p0[xx + 3], p1[xx + 3], p2[xx + 3]);
            }
            if (cx == 7) {
                tR = max3f(p0[xx + 12], p1[xx + 12], p2[xx + 12]);
            }
            t2C[0] = max3f(tL, t[0], t[1]);
            #pragma unroll
            for (int j = 1; j < 7; ++j) t2C[j] = max3f(t[j - 1], t[j], t[j + 1]);
            t2C[7] = max3f(t[6], t[7], tR);
        }

        // ---- E: output plane z = zz-3: relu(raw - max over t2 planes)
        if (zz >= z0 + 3) {
            const int z = zz - 3;
            float* op = ovol + ((size_t)z * H_ + (h0 + ty)) * W_ + (w0 + xx);
            float o[8];
            #pragma unroll
            for (int j = 0; j < 8; ++j) {
                float opened = max3f(t2A[j], t2B[j], t2C[j]);
                float v = rw0[j] - opened;
                o[j] = v > 0.f ? v : 0.f;
            }
            *(float4*)op       = make_float4(o[0], o[1], o[2], o[3]);
            *(float4*)(op + 4) = make_float4(o[4], o[5], o[6], o[7]);
        }

        // ---- shift register pipelines
        #pragma unroll
        for (int j = 0; j < 8; ++j) {
            t2A[j] = t2B[j]; t2B[j] = t2C[j];
            rw0[j] = rw1[j]; rw1[j] = rw2[j];
        }
        cur ^= 1;
    }
}

extern "C" void kernel_launch(void* const* d_in, const int* in_sizes, int n_in,
                              void* d_out, int out_size, void* d_ws, size_t ws_size,
                              hipStream_t stream) {
    const float* img = (const float*)d_in[0];
    float* out = (float*)d_out;

    dim3 grid(W_ / TW, H_ / TH, NB * NCHUNK);   // (4, 8, 24) = 768 blocks
    dim3 block(256);
    soft_skel_v7<<<grid, block, 0, stream>>>(img, out);
}